// Round 1
// baseline (572.733 us; speedup 1.0000x reference)
//
#include <hip/hip_runtime.h>
#include <math.h>

// SH constants (match reference)
__device__ __constant__ float kC0 = 0.28209479177387814f;
__device__ __constant__ float kC1 = 0.4886025119029199f;
__device__ __constant__ float kC2[5] = {1.0925484305920792f, -1.0925484305920792f, 0.31539156525252005f, -1.0925484305920792f, 0.5462742152960396f};
__device__ __constant__ float kC3[7] = {-0.5900435899266435f, 2.890611442640554f, -0.4570457994644658f, 0.3731763325901154f, -0.4570457994644658f, 1.445305721320277f, -0.5900435899266435f};

__global__ __launch_bounds__(256) void gs_fwd_kernel(
    const float* __restrict__ xyz,
    const float* __restrict__ f_dc,
    const float* __restrict__ f_rest,
    const float* __restrict__ scaling,
    const float* __restrict__ rotation,
    const float* __restrict__ opacity,
    const float* __restrict__ campos,
    const float* __restrict__ scaling_modifier,
    float* __restrict__ out,
    int N)
{
    const int n = blockIdx.x * blockDim.x + threadIdx.x;
    if (n >= N) return;

    const float cx = campos[0], cy = campos[1], cz = campos[2];
    const float sm = scaling_modifier[0];

    float* __restrict__ out_points = out;
    float* __restrict__ out_opac   = out + (size_t)3 * N;
    float* __restrict__ out_colors = out + (size_t)4 * N;
    float* __restrict__ out_cov    = out + (size_t)7 * N;

    // ---- points (copy) ----
    const float px = xyz[3 * (size_t)n + 0];
    const float py = xyz[3 * (size_t)n + 1];
    const float pz = xyz[3 * (size_t)n + 2];
    out_points[3 * (size_t)n + 0] = px;
    out_points[3 * (size_t)n + 1] = py;
    out_points[3 * (size_t)n + 2] = pz;

    // ---- opacity: sigmoid ----
    const float o = opacity[n];
    out_opac[n] = 1.0f / (1.0f + expf(-o));

    // ---- view direction ----
    float dx = px - cx, dy = py - cy, dz = pz - cz;
    const float inv_len = 1.0f / sqrtf(dx * dx + dy * dy + dz * dz);
    const float x = dx * inv_len, y = dy * inv_len, z = dz * inv_len;

    const float xx = x * x, yy = y * y, zz = z * z;
    const float xy = x * y, yz = y * z, xz = x * z;

    // ---- SH basis values (16) ----
    float b[16];
    b[0]  = kC0;
    b[1]  = -kC1 * y;
    b[2]  = kC1 * z;
    b[3]  = -kC1 * x;
    b[4]  = kC2[0] * xy;
    b[5]  = kC2[1] * yz;
    b[6]  = kC2[2] * (2.0f * zz - xx - yy);
    b[7]  = kC2[3] * xz;
    b[8]  = kC2[4] * (xx - yy);
    b[9]  = kC3[0] * y * (3.0f * xx - yy);
    b[10] = kC3[1] * xy * z;
    b[11] = kC3[2] * y * (4.0f * zz - xx - yy);
    b[12] = kC3[3] * z * (2.0f * zz - 3.0f * xx - 3.0f * yy);
    b[13] = kC3[4] * x * (4.0f * zz - xx - yy);
    b[14] = kC3[5] * z * (xx - yy);
    b[15] = kC3[6] * x * (xx - 3.0f * yy);

    // ---- SH dot with coefficients (features interleaved [k][c]) ----
    const float* __restrict__ fd = f_dc + 3 * (size_t)n;    // k = 0
    const float* __restrict__ fr = f_rest + 45 * (size_t)n; // k = 1..15

    float r0 = b[0] * fd[0];
    float r1 = b[0] * fd[1];
    float r2 = b[0] * fd[2];
#pragma unroll
    for (int k = 0; k < 15; ++k) {
        const float bk = b[k + 1];
        r0 = fmaf(bk, fr[3 * k + 0], r0);
        r1 = fmaf(bk, fr[3 * k + 1], r1);
        r2 = fmaf(bk, fr[3 * k + 2], r2);
    }
    out_colors[3 * (size_t)n + 0] = fmaxf(r0 + 0.5f, 0.0f);
    out_colors[3 * (size_t)n + 1] = fmaxf(r1 + 0.5f, 0.0f);
    out_colors[3 * (size_t)n + 2] = fmaxf(r2 + 0.5f, 0.0f);

    // ---- covariance ----
    const float4 q4 = *reinterpret_cast<const float4*>(rotation + 4 * (size_t)n); // 16B aligned
    const float qinv = 1.0f / sqrtf(q4.x * q4.x + q4.y * q4.y + q4.z * q4.z + q4.w * q4.w);
    const float qw = q4.x * qinv, qx = q4.y * qinv, qy = q4.z * qinv, qz = q4.w * qinv;

    const float R00 = 1.0f - 2.0f * (qy * qy + qz * qz);
    const float R01 = 2.0f * (qx * qy - qw * qz);
    const float R02 = 2.0f * (qx * qz + qw * qy);
    const float R10 = 2.0f * (qx * qy + qw * qz);
    const float R11 = 1.0f - 2.0f * (qx * qx + qz * qz);
    const float R12 = 2.0f * (qy * qz - qw * qx);
    const float R20 = 2.0f * (qx * qz - qw * qy);
    const float R21 = 2.0f * (qy * qz + qw * qx);
    const float R22 = 1.0f - 2.0f * (qx * qx + qy * qy);

    const float s0 = sm * expf(scaling[3 * (size_t)n + 0]);
    const float s1 = sm * expf(scaling[3 * (size_t)n + 1]);
    const float s2 = sm * expf(scaling[3 * (size_t)n + 2]);

    const float L00 = R00 * s0, L01 = R01 * s1, L02 = R02 * s2;
    const float L10 = R10 * s0, L11 = R11 * s1, L12 = R12 * s2;
    const float L20 = R20 * s0, L21 = R21 * s1, L22 = R22 * s2;

    out_cov[6 * (size_t)n + 0] = L00 * L00 + L01 * L01 + L02 * L02; // (0,0)
    out_cov[6 * (size_t)n + 1] = L00 * L10 + L01 * L11 + L02 * L12; // (0,1)
    out_cov[6 * (size_t)n + 2] = L00 * L20 + L01 * L21 + L02 * L22; // (0,2)
    out_cov[6 * (size_t)n + 3] = L10 * L10 + L11 * L11 + L12 * L12; // (1,1)
    out_cov[6 * (size_t)n + 4] = L10 * L20 + L11 * L21 + L12 * L22; // (1,2)
    out_cov[6 * (size_t)n + 5] = L20 * L20 + L21 * L21 + L22 * L22; // (2,2)
}

extern "C" void kernel_launch(void* const* d_in, const int* in_sizes, int n_in,
                              void* d_out, int out_size, void* d_ws, size_t ws_size,
                              hipStream_t stream) {
    const float* xyz      = (const float*)d_in[0];
    const float* f_dc     = (const float*)d_in[1];
    const float* f_rest   = (const float*)d_in[2];
    const float* scaling  = (const float*)d_in[3];
    const float* rotation = (const float*)d_in[4];
    const float* opacity  = (const float*)d_in[5];
    const float* campos   = (const float*)d_in[6];
    const float* scalemod = (const float*)d_in[7];
    float* out = (float*)d_out;

    const int N = in_sizes[0] / 3;
    const int block = 256;
    const int grid = (N + block - 1) / block;
    gs_fwd_kernel<<<grid, block, 0, stream>>>(xyz, f_dc, f_rest, scaling, rotation,
                                              opacity, campos, scalemod, out, N);
}

// Round 2
// 566.693 us; speedup vs baseline: 1.0107x; 1.0107x over previous
//
#include <hip/hip_runtime.h>
#include <math.h>

constexpr int BLOCK = 256;
constexpr int KREST = 45;                 // 15 SH coeffs x 3 channels
constexpr int FR_FLOATS = KREST * BLOCK;  // 11520 floats = 45 KB
constexpr int FR_VEC4 = FR_FLOATS / 4;    // 2880 float4
constexpr int FR_VEC4_ITERS = FR_VEC4 / BLOCK;          // 11 full float4 iterations
constexpr int FR_SCALAR_OFF = FR_VEC4_ITERS * BLOCK * 4; // 11264: remaining 256 floats

// SH constants (match reference)
__device__ __constant__ float kC0 = 0.28209479177387814f;
__device__ __constant__ float kC1 = 0.4886025119029199f;
__device__ __constant__ float kC2[5] = {1.0925484305920792f, -1.0925484305920792f, 0.31539156525252005f, -1.0925484305920792f, 0.5462742152960396f};
__device__ __constant__ float kC3[7] = {-0.5900435899266435f, 2.890611442640554f, -0.4570457994644658f, 0.3731763325901154f, -0.4570457994644658f, 1.445305721320277f, -0.5900435899266435f};

__global__ __launch_bounds__(BLOCK) void gs_fwd_kernel(
    const float* __restrict__ xyz,
    const float* __restrict__ f_dc,
    const float* __restrict__ f_rest,
    const float* __restrict__ scaling,
    const float* __restrict__ rotation,
    const float* __restrict__ opacity,
    const float* __restrict__ campos,
    const float* __restrict__ scaling_modifier,
    float* __restrict__ out,
    int N)
{
    __shared__ float s_fr[FR_FLOATS]; // 45 KB -> 3 blocks/CU, 12 waves/CU

    const int base = blockIdx.x * BLOCK;
    const int t = threadIdx.x;
    const int n = base + t;

    // ---- cooperative coalesced staging of f_rest[45*base .. 45*(base+256)) ----
    const float* __restrict__ src = f_rest + (size_t)KREST * base;
    if (base + BLOCK <= N) {
        // full block: region is 16B-aligned (180*256*blockIdx bytes)
        const float4* __restrict__ src4 = reinterpret_cast<const float4*>(src);
        float4* dst4 = reinterpret_cast<float4*>(s_fr);
#pragma unroll
        for (int i = 0; i < FR_VEC4_ITERS; ++i)
            dst4[i * BLOCK + t] = src4[i * BLOCK + t];
        s_fr[FR_SCALAR_OFF + t] = src[FR_SCALAR_OFF + t];
    } else {
        const int rem = KREST * (N - base);
        for (int j = t; j < rem; j += BLOCK)
            s_fr[j] = src[j];
    }
    __syncthreads();

    if (n >= N) return;

    const float cx = campos[0], cy = campos[1], cz = campos[2];
    const float sm = scaling_modifier[0];

    float* __restrict__ out_points = out;
    float* __restrict__ out_opac   = out + (size_t)3 * N;
    float* __restrict__ out_colors = out + (size_t)4 * N;
    float* __restrict__ out_cov    = out + (size_t)7 * N;

    // ---- points (copy) ----
    const float px = xyz[3 * (size_t)n + 0];
    const float py = xyz[3 * (size_t)n + 1];
    const float pz = xyz[3 * (size_t)n + 2];
    out_points[3 * (size_t)n + 0] = px;
    out_points[3 * (size_t)n + 1] = py;
    out_points[3 * (size_t)n + 2] = pz;

    // ---- opacity: sigmoid ----
    const float o = opacity[n];
    out_opac[n] = 1.0f / (1.0f + expf(-o));

    // ---- view direction ----
    const float dx = px - cx, dy = py - cy, dz = pz - cz;
    const float inv_len = 1.0f / sqrtf(dx * dx + dy * dy + dz * dz);
    const float x = dx * inv_len, y = dy * inv_len, z = dz * inv_len;

    const float xx = x * x, yy = y * y, zz = z * z;
    const float xy = x * y, yz = y * z, xz = x * z;

    // ---- SH basis values (16) ----
    float b[16];
    b[0]  = kC0;
    b[1]  = -kC1 * y;
    b[2]  = kC1 * z;
    b[3]  = -kC1 * x;
    b[4]  = kC2[0] * xy;
    b[5]  = kC2[1] * yz;
    b[6]  = kC2[2] * (2.0f * zz - xx - yy);
    b[7]  = kC2[3] * xz;
    b[8]  = kC2[4] * (xx - yy);
    b[9]  = kC3[0] * y * (3.0f * xx - yy);
    b[10] = kC3[1] * xy * z;
    b[11] = kC3[2] * y * (4.0f * zz - xx - yy);
    b[12] = kC3[3] * z * (2.0f * zz - 3.0f * xx - 3.0f * yy);
    b[13] = kC3[4] * x * (4.0f * zz - xx - yy);
    b[14] = kC3[5] * z * (xx - yy);
    b[15] = kC3[6] * x * (xx - 3.0f * yy);

    // ---- SH dot with coefficients ----
    const float* __restrict__ fd = f_dc + 3 * (size_t)n;  // k = 0 (global, stride-12: line-efficient)
    const float* __restrict__ fr = &s_fr[KREST * t];      // k = 1..15 from LDS (bank-conflict-free)

    float r0 = b[0] * fd[0];
    float r1 = b[0] * fd[1];
    float r2 = b[0] * fd[2];
#pragma unroll
    for (int k = 0; k < 15; ++k) {
        const float bk = b[k + 1];
        r0 = fmaf(bk, fr[3 * k + 0], r0);
        r1 = fmaf(bk, fr[3 * k + 1], r1);
        r2 = fmaf(bk, fr[3 * k + 2], r2);
    }
    out_colors[3 * (size_t)n + 0] = fmaxf(r0 + 0.5f, 0.0f);
    out_colors[3 * (size_t)n + 1] = fmaxf(r1 + 0.5f, 0.0f);
    out_colors[3 * (size_t)n + 2] = fmaxf(r2 + 0.5f, 0.0f);

    // ---- covariance ----
    const float4 q4 = *reinterpret_cast<const float4*>(rotation + 4 * (size_t)n); // 16B aligned
    const float qinv = 1.0f / sqrtf(q4.x * q4.x + q4.y * q4.y + q4.z * q4.z + q4.w * q4.w);
    const float qw = q4.x * qinv, qx = q4.y * qinv, qy = q4.z * qinv, qz = q4.w * qinv;

    const float R00 = 1.0f - 2.0f * (qy * qy + qz * qz);
    const float R01 = 2.0f * (qx * qy - qw * qz);
    const float R02 = 2.0f * (qx * qz + qw * qy);
    const float R10 = 2.0f * (qx * qy + qw * qz);
    const float R11 = 1.0f - 2.0f * (qx * qx + qz * qz);
    const float R12 = 2.0f * (qy * qz - qw * qx);
    const float R20 = 2.0f * (qx * qz - qw * qy);
    const float R21 = 2.0f * (qy * qz + qw * qx);
    const float R22 = 1.0f - 2.0f * (qx * qx + qy * qy);

    const float s0 = sm * expf(scaling[3 * (size_t)n + 0]);
    const float s1 = sm * expf(scaling[3 * (size_t)n + 1]);
    const float s2 = sm * expf(scaling[3 * (size_t)n + 2]);

    const float L00 = R00 * s0, L01 = R01 * s1, L02 = R02 * s2;
    const float L10 = R10 * s0, L11 = R11 * s1, L12 = R12 * s2;
    const float L20 = R20 * s0, L21 = R21 * s1, L22 = R22 * s2;

    out_cov[6 * (size_t)n + 0] = L00 * L00 + L01 * L01 + L02 * L02; // (0,0)
    out_cov[6 * (size_t)n + 1] = L00 * L10 + L01 * L11 + L02 * L12; // (0,1)
    out_cov[6 * (size_t)n + 2] = L00 * L20 + L01 * L21 + L02 * L22; // (0,2)
    out_cov[6 * (size_t)n + 3] = L10 * L10 + L11 * L11 + L12 * L12; // (1,1)
    out_cov[6 * (size_t)n + 4] = L10 * L20 + L11 * L21 + L12 * L22; // (1,2)
    out_cov[6 * (size_t)n + 5] = L20 * L20 + L21 * L21 + L22 * L22; // (2,2)
}

extern "C" void kernel_launch(void* const* d_in, const int* in_sizes, int n_in,
                              void* d_out, int out_size, void* d_ws, size_t ws_size,
                              hipStream_t stream) {
    const float* xyz      = (const float*)d_in[0];
    const float* f_dc     = (const float*)d_in[1];
    const float* f_rest   = (const float*)d_in[2];
    const float* scaling  = (const float*)d_in[3];
    const float* rotation = (const float*)d_in[4];
    const float* opacity  = (const float*)d_in[5];
    const float* campos   = (const float*)d_in[6];
    const float* scalemod = (const float*)d_in[7];
    float* out = (float*)d_out;

    const int N = in_sizes[0] / 3;
    const int grid = (N + BLOCK - 1) / BLOCK;
    gs_fwd_kernel<<<grid, BLOCK, 0, stream>>>(xyz, f_dc, f_rest, scaling, rotation,
                                              opacity, campos, scalemod, out, N);
}